// Round 2
// 804.341 us; speedup vs baseline: 1.0991x; 1.0991x over previous
//
#include <hip/hip_runtime.h>
#include <math.h>

#define T_SEQ 1024
#define CM 256
#define HEADS 8
#define DHH 32
#define NB 4
#define TT (T_SEQ * T_SEQ)

typedef __attribute__((ext_vector_type(8))) short bf16x8;
typedef __attribute__((ext_vector_type(4))) float f32x4;

__device__ __forceinline__ unsigned short f2bf(float f) {
    unsigned u = __builtin_bit_cast(unsigned, f);
    unsigned r = (u + 0x7FFFu + ((u >> 16) & 1u)) >> 16;
    return (unsigned short)r;
}

__device__ __forceinline__ bf16x8 cvt8(const float4 a0, const float4 a1) {
    bf16x8 t;
    t[0] = (short)f2bf(a0.x); t[1] = (short)f2bf(a0.y);
    t[2] = (short)f2bf(a0.z); t[3] = (short)f2bf(a0.w);
    t[4] = (short)f2bf(a1.x); t[5] = (short)f2bf(a1.y);
    t[6] = (short)f2bf(a1.z); t[7] = (short)f2bf(a1.w);
    return t;
}

// ---------------------------------------------------------------------------
// Setup kernels (tiny, off critical path)
// ---------------------------------------------------------------------------
// Wt[n][k] = W[k][n], K fixed at 256. Output-coalesced bf16 writes.
__global__ __launch_bounds__(256) void transpose_cast_kernel(const float* __restrict__ W,
                                                             unsigned short* __restrict__ Wt,
                                                             int cols) {
    int o = blockIdx.x * 256 + threadIdx.x;
    int n = o >> 8, k = o & 255;
    Wt[o] = f2bf(W[k * cols + n]);
}

// WbT[h][k] = Wb[k][h] for h<8, zero-pad h=8..15.  (16 x 128 bf16)
__global__ __launch_bounds__(256) void pad_wb_kernel(const float* __restrict__ Wb,
                                                     unsigned short* __restrict__ WbT) {
    int idx = blockIdx.x * 256 + threadIdx.x;   // 2048 total
    int h = idx >> 7, k = idx & 127;
    WbT[idx] = (h < 8) ? f2bf(Wb[k * 8 + h]) : (unsigned short)0;
}

// ---------------------------------------------------------------------------
// K1: qkv = x @ Wqkv via bf16 MFMA, f32->bf16 cast fused into A-frag load.
// Grid (8 heads, 64 m-tiles); each wave: 16 rows x 128 vcols (1 head).
// q pre-scaled by DH^-0.5; v written transposed [B,H,DH,T].
// ---------------------------------------------------------------------------
__global__ __launch_bounds__(256) void qkv_gemm_mfma(const float* __restrict__ x,
                                                     const unsigned short* __restrict__ Wt,
                                                     unsigned short* __restrict__ qb,
                                                     unsigned short* __restrict__ kb,
                                                     unsigned short* __restrict__ vT,
                                                     float* __restrict__ g) {
    const int tid = threadIdx.x;
    const int w = tid >> 6;
    const int lane = tid & 63;
    const int n16 = lane & 15;
    const int quad = lane >> 4;
    const int m0 = blockIdx.y * 64 + w * 16;
    const int h = blockIdx.x;
    const float scale = 0.17677669529663687f;

    bf16x8 afr[8];
    #pragma unroll
    for (int kc = 0; kc < 8; ++kc) {
        const float* src = &x[(m0 + n16) * 256 + kc * 32 + quad * 8];
        float4 a0 = *(const float4*)src;
        float4 a1 = *(const float4*)(src + 4);
        afr[kc] = cvt8(a0, a1);
    }

    #pragma unroll
    for (int s = 0; s < 8; ++s) {
        const int kk = s >> 1;
        const int dhi = s & 1;
        const int c = (dhi * 16 + n16) * 32 + kk * 8 + h;
        f32x4 acc = {0.f, 0.f, 0.f, 0.f};
        #pragma unroll
        for (int kc = 0; kc < 8; ++kc) {
            bf16x8 bfr = *(const bf16x8*)&Wt[c * 256 + kc * 32 + quad * 8];
            acc = __builtin_amdgcn_mfma_f32_16x16x32_bf16(afr[kc], bfr, acc, 0, 0, 0);
        }
        const int d = dhi * 16 + n16;
        #pragma unroll
        for (int r = 0; r < 4; ++r) {
            int m = m0 + quad * 4 + r;
            int b = m >> 10, t = m & 1023;
            int bh = b * HEADS + h;
            float val = acc[r];
            if (kk == 0)      qb[(bh * T_SEQ + t) * DHH + d] = f2bf(val * scale);
            else if (kk == 1) kb[(bh * T_SEQ + t) * DHH + d] = f2bf(val);
            else if (kk == 2) vT[(bh * DHH + d) * T_SEQ + t] = f2bf(val);
            else              g[(bh * T_SEQ + t) * DHH + d] = val;
        }
    }
}

// ---------------------------------------------------------------------------
// K2: pb[h][p] = bias_rep[p][:128] . Wb[:][h] + bb[h]  via MFMA (K=128).
// Replaces the shfl-butterfly reduction (320 DS ops/wave -> 0 DS ops).
// Each wave: one 16-row tile; A-frags loaded straight from global f32,
// converted to bf16 in-register; B = zero-padded WbT (L2-resident).
// ---------------------------------------------------------------------------
__global__ __launch_bounds__(256) void pair_bias_mfma(const float* __restrict__ bias_rep,
                                                      const unsigned short* __restrict__ WbT,
                                                      const float* __restrict__ bb,
                                                      float* __restrict__ pb) {
    const int tid = threadIdx.x;
    const int w = tid >> 6;
    const int lane = tid & 63;
    const int n16 = lane & 15;
    const int quad = lane >> 4;
    const int p0 = blockIdx.x * 64 + w * 16;

    bf16x8 afr[4];
    #pragma unroll
    for (int kc = 0; kc < 4; ++kc) {
        const float* src = &bias_rep[(long long)(p0 + n16) * 128 + kc * 32 + quad * 8];
        float4 a0 = *(const float4*)src;
        float4 a1 = *(const float4*)(src + 4);
        afr[kc] = cvt8(a0, a1);
    }

    f32x4 acc = {0.f, 0.f, 0.f, 0.f};
    #pragma unroll
    for (int kc = 0; kc < 4; ++kc) {
        bf16x8 bfr = *(const bf16x8*)&WbT[n16 * 128 + kc * 32 + quad * 8];
        acc = __builtin_amdgcn_mfma_f32_16x16x32_bf16(afr[kc], bfr, acc, 0, 0, 0);
    }

    if (n16 < 8) {
        float bbv = bb[n16];
        #pragma unroll
        for (int r = 0; r < 4; ++r)
            pb[(long long)n16 * TT + p0 + quad * 4 + r] = acc[r] + bbv;
    }
}

// ---------------------------------------------------------------------------
// K3: flash attention, bf16 MFMA, barrier-free (each wave owns 16 Q rows).
// Changes vs prev: pb loads hoisted ahead of QK MFMAs; per-tile sum-reduce
// eliminated (per-lane partial l, reduced once in epilogue); s_setprio
// around MFMA clusters (independent waves -> scheduler has room, m191).
// ---------------------------------------------------------------------------
__global__ __launch_bounds__(256) void attn_mfma(const unsigned short* __restrict__ qb,
                                                 const unsigned short* __restrict__ kb,
                                                 const unsigned short* __restrict__ vT,
                                                 const float* __restrict__ g,
                                                 const float* __restrict__ pb,
                                                 unsigned short* __restrict__ gated) {
    __shared__ unsigned short Ps[4][16][72];   // per-wave 16x64 strip
    const int tid = threadIdx.x;
    const int w = tid >> 6;
    const int lane = tid & 63;
    const int n16 = lane & 15;
    const int quad = lane >> 4;
    const int it0 = blockIdx.x * 64;
    const int h = blockIdx.y, b = blockIdx.z;
    const int bh = b * HEADS + h;
    const int qrow0 = it0 + w * 16;

    bf16x8 qfr = *(const bf16x8*)&qb[(bh * T_SEQ + qrow0 + n16) * DHH + quad * 8];

    float m_i[4] = {-INFINITY, -INFINITY, -INFINITY, -INFINITY};
    float l_i[4] = {0.f, 0.f, 0.f, 0.f};     // per-lane partials (cols n16, n16+16, +32, +48)
    f32x4 O0 = {0.f, 0.f, 0.f, 0.f};
    f32x4 O1 = {0.f, 0.f, 0.f, 0.f};

    for (int jt = 0; jt < 16; ++jt) {
        const int j0 = jt * 64;
        // hoist pair-bias loads: overlap their latency with the QK MFMAs
        float pbv[4][4];
        #pragma unroll
        for (int s4 = 0; s4 < 4; ++s4)
            #pragma unroll
            for (int r = 0; r < 4; ++r)
                pbv[s4][r] = pb[h * TT + (qrow0 + quad * 4 + r) * T_SEQ + j0 + s4 * 16 + n16];

        f32x4 S[4];
        __builtin_amdgcn_s_setprio(1);
        #pragma unroll
        for (int s4 = 0; s4 < 4; ++s4) {
            bf16x8 kfr = *(const bf16x8*)&kb[(bh * T_SEQ + j0 + s4 * 16 + n16) * DHH + quad * 8];
            f32x4 z = {0.f, 0.f, 0.f, 0.f};
            S[s4] = __builtin_amdgcn_mfma_f32_16x16x32_bf16(qfr, kfr, z, 0, 0, 0);
        }
        __builtin_amdgcn_s_setprio(0);

        #pragma unroll
        for (int s4 = 0; s4 < 4; ++s4)
            #pragma unroll
            for (int r = 0; r < 4; ++r)
                S[s4][r] += pbv[s4][r];

        // online softmax: max-reduce across the 16-lane row group; l stays per-lane
        #pragma unroll
        for (int r = 0; r < 4; ++r) {
            float mx = fmaxf(fmaxf(S[0][r], S[1][r]), fmaxf(S[2][r], S[3][r]));
            mx = fmaxf(mx, __shfl_xor(mx, 1));
            mx = fmaxf(mx, __shfl_xor(mx, 2));
            mx = fmaxf(mx, __shfl_xor(mx, 4));
            mx = fmaxf(mx, __shfl_xor(mx, 8));
            float mnew = fmaxf(m_i[r], mx);
            float alpha = __expf(m_i[r] - mnew);
            m_i[r] = mnew;
            float lsum = 0.f;
            #pragma unroll
            for (int s4 = 0; s4 < 4; ++s4) {
                float p = __expf(S[s4][r] - mnew);
                S[s4][r] = p;
                lsum += p;
            }
            l_i[r] = l_i[r] * alpha + lsum;
            O0[r] *= alpha;
            O1[r] *= alpha;
        }

        // P: C-layout -> LDS -> A-layout (per-wave strip, no barrier needed)
        #pragma unroll
        for (int s4 = 0; s4 < 4; ++s4)
            #pragma unroll
            for (int r = 0; r < 4; ++r)
                Ps[w][quad * 4 + r][s4 * 16 + n16] = f2bf(S[s4][r]);
        __builtin_amdgcn_s_setprio(1);
        #pragma unroll
        for (int kc = 0; kc < 2; ++kc) {
            bf16x8 pfr = *(const bf16x8*)&Ps[w][n16][kc * 32 + quad * 8];
            bf16x8 v0 = *(const bf16x8*)&vT[(bh * DHH + n16) * T_SEQ + j0 + kc * 32 + quad * 8];
            bf16x8 v1 = *(const bf16x8*)&vT[(bh * DHH + 16 + n16) * T_SEQ + j0 + kc * 32 + quad * 8];
            O0 = __builtin_amdgcn_mfma_f32_16x16x32_bf16(pfr, v0, O0, 0, 0, 0);
            O1 = __builtin_amdgcn_mfma_f32_16x16x32_bf16(pfr, v1, O1, 0, 0, 0);
        }
        __builtin_amdgcn_s_setprio(0);
    }

    // epilogue: finish l reduction (once), 1/l, sigmoid gate, bf16 store
    #pragma unroll
    for (int r = 0; r < 4; ++r) {
        float lr = l_i[r];
        lr += __shfl_xor(lr, 1);
        lr += __shfl_xor(lr, 2);
        lr += __shfl_xor(lr, 4);
        lr += __shfl_xor(lr, 8);
        int t = qrow0 + quad * 4 + r;
        float linv = 1.f / lr;
        float g0 = g[(bh * T_SEQ + t) * DHH + n16];
        float g1 = g[(bh * T_SEQ + t) * DHH + 16 + n16];
        float o0 = O0[r] * linv / (1.f + __expf(-g0));
        float o1 = O1[r] * linv / (1.f + __expf(-g1));
        gated[(b * T_SEQ + t) * CM + h * DHH + n16] = f2bf(o0);
        gated[(b * T_SEQ + t) * CM + h * DHH + 16 + n16] = f2bf(o1);
    }
}

// ---------------------------------------------------------------------------
// K4: y = gated @ W0 via bf16 MFMA. 1 wave/block, 16 rows x 256 cols.
// ---------------------------------------------------------------------------
__global__ __launch_bounds__(64) void out_gemm_mfma(const unsigned short* __restrict__ gb,
                                                    const unsigned short* __restrict__ W0t,
                                                    float* __restrict__ y) {
    const int lane = threadIdx.x;
    const int n16 = lane & 15;
    const int quad = lane >> 4;
    const int m0 = blockIdx.x * 16;

    bf16x8 afr[8];
    #pragma unroll
    for (int kc = 0; kc < 8; ++kc)
        afr[kc] = *(const bf16x8*)&gb[(m0 + n16) * 256 + kc * 32 + quad * 8];

    #pragma unroll
    for (int s = 0; s < 16; ++s) {
        f32x4 acc = {0.f, 0.f, 0.f, 0.f};
        #pragma unroll
        for (int kc = 0; kc < 8; ++kc) {
            bf16x8 bfr = *(const bf16x8*)&W0t[(s * 16 + n16) * 256 + kc * 32 + quad * 8];
            acc = __builtin_amdgcn_mfma_f32_16x16x32_bf16(afr[kc], bfr, acc, 0, 0, 0);
        }
        #pragma unroll
        for (int r = 0; r < 4; ++r)
            y[(m0 + quad * 4 + r) * 256 + s * 16 + n16] = acc[r];
    }
}

// ---------------------------------------------------------------------------
extern "C" void kernel_launch(void* const* d_in, const int* in_sizes, int n_in,
                              void* d_out, int out_size, void* d_ws, size_t ws_size,
                              hipStream_t stream) {
    const float* x        = (const float*)d_in[0];   // [4,1024,256]
    const float* bias_rep = (const float*)d_in[1];   // [1024,1024,128]
    const float* Wqkv     = (const float*)d_in[2];   // [256,1024]
    const float* W0       = (const float*)d_in[3];   // [256,256]
    const float* Wb       = (const float*)d_in[4];   // [128,8]
    const float* bb       = (const float*)d_in[5];   // [8]

    char* ws = (char*)d_ws;
    float*          pb    = (float*)ws;                 ws += 8LL * 1024 * 1024 * 4;  // 32 MB
    float*          g     = (float*)ws;                 ws += 4LL * 1024 * 1024;      // 4 MB
    unsigned short* qb    = (unsigned short*)ws;        ws += 2LL * 1024 * 1024;      // 2 MB
    unsigned short* kb    = (unsigned short*)ws;        ws += 2LL * 1024 * 1024;
    unsigned short* vT    = (unsigned short*)ws;        ws += 2LL * 1024 * 1024;
    unsigned short* gated = (unsigned short*)ws;        ws += 2LL * 1024 * 1024;
    unsigned short* Wt    = (unsigned short*)ws;        ws += 512LL * 1024;
    unsigned short* W0t   = (unsigned short*)ws;        ws += 128LL * 1024;
    unsigned short* WbT   = (unsigned short*)ws;        // 4 KB
    float* y = (float*)d_out;

    transpose_cast_kernel<<<1024, 256, 0, stream>>>(Wqkv, Wt, 1024);
    transpose_cast_kernel<<<256, 256, 0, stream>>>(W0, W0t, 256);
    pad_wb_kernel<<<8, 256, 0, stream>>>(Wb, WbT);
    qkv_gemm_mfma<<<dim3(8, 64), 256, 0, stream>>>(x, Wt, qb, kb, vT, g);
    pair_bias_mfma<<<16384, 256, 0, stream>>>(bias_rep, WbT, bb, pb);
    attn_mfma<<<dim3(16, HEADS, NB), 256, 0, stream>>>(qb, kb, vT, g, pb, gated);
    out_gemm_mfma<<<256, 64, 0, stream>>>(gated, W0t, y);
}

// Round 3
// 757.392 us; speedup vs baseline: 1.1672x; 1.0620x over previous
//
#include <hip/hip_runtime.h>
#include <math.h>

#define T_SEQ 1024
#define CM 256
#define HEADS 8
#define DHH 32
#define NB 4
#define TT (T_SEQ * T_SEQ)

typedef __attribute__((ext_vector_type(8))) short bf16x8;
typedef __attribute__((ext_vector_type(4))) float f32x4;

__device__ __forceinline__ unsigned short f2bf(float f) {
    unsigned u = __builtin_bit_cast(unsigned, f);
    unsigned r = (u + 0x7FFFu + ((u >> 16) & 1u)) >> 16;
    return (unsigned short)r;
}

__device__ __forceinline__ bf16x8 cvt8(const float4 a0, const float4 a1) {
    bf16x8 t;
    t[0] = (short)f2bf(a0.x); t[1] = (short)f2bf(a0.y);
    t[2] = (short)f2bf(a0.z); t[3] = (short)f2bf(a0.w);
    t[4] = (short)f2bf(a1.x); t[5] = (short)f2bf(a1.y);
    t[6] = (short)f2bf(a1.z); t[7] = (short)f2bf(a1.w);
    return t;
}

// ---------------------------------------------------------------------------
// Setup: Wt[n][k] = W[k][n] (K fixed 256), coalesced via 32x32 LDS tile.
// grid (cols/32, 256/32), 256 threads.
// ---------------------------------------------------------------------------
__global__ __launch_bounds__(256) void transpose_cast_lds(const float* __restrict__ W,
                                                          unsigned short* __restrict__ Wt,
                                                          int cols) {
    __shared__ float tile[32][33];
    const int n0 = blockIdx.x * 32, k0 = blockIdx.y * 32;
    const int r = threadIdx.x >> 3;
    const int c4 = (threadIdx.x & 7) * 4;
    float4 v = *(const float4*)&W[(k0 + r) * cols + n0 + c4];
    tile[r][c4 + 0] = v.x; tile[r][c4 + 1] = v.y;
    tile[r][c4 + 2] = v.z; tile[r][c4 + 3] = v.w;
    __syncthreads();
    ushort4 o;
    o.x = f2bf(tile[c4 + 0][r]);
    o.y = f2bf(tile[c4 + 1][r]);
    o.z = f2bf(tile[c4 + 2][r]);
    o.w = f2bf(tile[c4 + 3][r]);
    *(ushort4*)&Wt[(n0 + r) * 256 + k0 + c4] = o;
}

// WbT[h][k] = Wb[k][h] for h<8, zero-pad h=8..15.  (16 x 128 bf16)
__global__ __launch_bounds__(256) void pad_wb_kernel(const float* __restrict__ Wb,
                                                     unsigned short* __restrict__ WbT) {
    int idx = blockIdx.x * 256 + threadIdx.x;   // 2048 total
    int h = idx >> 7, k = idx & 127;
    WbT[idx] = (h < 8) ? f2bf(Wb[k * 8 + h]) : (unsigned short)0;
}

// ---------------------------------------------------------------------------
// K1: qkv = x @ Wqkv via bf16 MFMA, f32->bf16 cast fused into A-frag load.
// Grid (4 h-pairs, 64 m-tiles): 2 heads/block halves redundant x reads/cvt.
// q pre-scaled by DH^-0.5; v written transposed [B,H,DH,T].
// ---------------------------------------------------------------------------
__global__ __launch_bounds__(256) void qkv_gemm_mfma(const float* __restrict__ x,
                                                     const unsigned short* __restrict__ Wt,
                                                     unsigned short* __restrict__ qb,
                                                     unsigned short* __restrict__ kb,
                                                     unsigned short* __restrict__ vT,
                                                     float* __restrict__ g) {
    const int tid = threadIdx.x;
    const int w = tid >> 6;
    const int lane = tid & 63;
    const int n16 = lane & 15;
    const int quad = lane >> 4;
    const int m0 = blockIdx.y * 64 + w * 16;
    const int hbase = blockIdx.x * 2;
    const float scale = 0.17677669529663687f;

    bf16x8 afr[8];
    #pragma unroll
    for (int kc = 0; kc < 8; ++kc) {
        const float* src = &x[(m0 + n16) * 256 + kc * 32 + quad * 8];
        float4 a0 = *(const float4*)src;
        float4 a1 = *(const float4*)(src + 4);
        afr[kc] = cvt8(a0, a1);
    }

    #pragma unroll
    for (int s = 0; s < 16; ++s) {
        const int h = hbase + (s >> 3);
        const int kk = (s >> 1) & 3;
        const int dhi = s & 1;
        const int c = (dhi * 16 + n16) * 32 + kk * 8 + h;
        f32x4 acc = {0.f, 0.f, 0.f, 0.f};
        #pragma unroll
        for (int kc = 0; kc < 8; ++kc) {
            bf16x8 bfr = *(const bf16x8*)&Wt[c * 256 + kc * 32 + quad * 8];
            acc = __builtin_amdgcn_mfma_f32_16x16x32_bf16(afr[kc], bfr, acc, 0, 0, 0);
        }
        const int d = dhi * 16 + n16;
        #pragma unroll
        for (int r = 0; r < 4; ++r) {
            int m = m0 + quad * 4 + r;
            int b = m >> 10, t = m & 1023;
            int bh = b * HEADS + h;
            float val = acc[r];
            if (kk == 0)      qb[(bh * T_SEQ + t) * DHH + d] = f2bf(val * scale);
            else if (kk == 1) kb[(bh * T_SEQ + t) * DHH + d] = f2bf(val);
            else if (kk == 2) vT[(bh * DHH + d) * T_SEQ + t] = f2bf(val);
            else              g[(bh * T_SEQ + t) * DHH + d] = val;
        }
    }
}

// ---------------------------------------------------------------------------
// K2: pb[h][p] = bias_rep[p][:128] . Wb[:][h] + bb[h]  via MFMA (K=128).
// Memory-bound at the 544 MB floor (~86 us).
// ---------------------------------------------------------------------------
__global__ __launch_bounds__(256) void pair_bias_mfma(const float* __restrict__ bias_rep,
                                                      const unsigned short* __restrict__ WbT,
                                                      const float* __restrict__ bb,
                                                      float* __restrict__ pb) {
    const int tid = threadIdx.x;
    const int w = tid >> 6;
    const int lane = tid & 63;
    const int n16 = lane & 15;
    const int quad = lane >> 4;
    const int p0 = blockIdx.x * 64 + w * 16;

    bf16x8 afr[4];
    #pragma unroll
    for (int kc = 0; kc < 4; ++kc) {
        const float* src = &bias_rep[(long long)(p0 + n16) * 128 + kc * 32 + quad * 8];
        float4 a0 = *(const float4*)src;
        float4 a1 = *(const float4*)(src + 4);
        afr[kc] = cvt8(a0, a1);
    }

    f32x4 acc = {0.f, 0.f, 0.f, 0.f};
    #pragma unroll
    for (int kc = 0; kc < 4; ++kc) {
        bf16x8 bfr = *(const bf16x8*)&WbT[n16 * 128 + kc * 32 + quad * 8];
        acc = __builtin_amdgcn_mfma_f32_16x16x32_bf16(afr[kc], bfr, acc, 0, 0, 0);
    }

    if (n16 < 8) {
        float bbv = bb[n16];
        #pragma unroll
        for (int r = 0; r < 4; ++r)
            pb[(long long)n16 * TT + p0 + quad * 4 + r] = acc[r] + bbv;
    }
}

// ---------------------------------------------------------------------------
// K3: flash attention, bf16 MFMA, barrier-free (each wave owns 16 Q rows).
// This round: pb + K fragment loads software-pipelined one j-tile ahead
// (manual 2x unroll, named A/B buffers -> static indexing, no scratch).
// ---------------------------------------------------------------------------
__global__ __launch_bounds__(256) void attn_mfma(const unsigned short* __restrict__ qb,
                                                 const unsigned short* __restrict__ kb,
                                                 const unsigned short* __restrict__ vT,
                                                 const float* __restrict__ g,
                                                 const float* __restrict__ pb,
                                                 unsigned short* __restrict__ gated) {
    __shared__ unsigned short Ps[4][16][72];   // per-wave 16x64 strip
    const int tid = threadIdx.x;
    const int w = tid >> 6;
    const int lane = tid & 63;
    const int n16 = lane & 15;
    const int quad = lane >> 4;
    const int it0 = blockIdx.x * 64;
    const int h = blockIdx.y, b = blockIdx.z;
    const int bh = b * HEADS + h;
    const int qrow0 = it0 + w * 16;

    bf16x8 qfr = *(const bf16x8*)&qb[(bh * T_SEQ + qrow0 + n16) * DHH + quad * 8];

    float m_i[4] = {-INFINITY, -INFINITY, -INFINITY, -INFINITY};
    float l_i[4] = {0.f, 0.f, 0.f, 0.f};     // per-lane partials
    f32x4 O0 = {0.f, 0.f, 0.f, 0.f};
    f32x4 O1 = {0.f, 0.f, 0.f, 0.f};

    float pbvA[4][4], pbvB[4][4];
    bf16x8 kfrA[4], kfrB[4];

#define PREFETCH(pbvX, kfrX, jtn) do {                                           \
    const int jn_ = (jtn) & 15;                                                  \
    const int jj_ = jn_ * 64;                                                    \
    _Pragma("unroll")                                                            \
    for (int s4 = 0; s4 < 4; ++s4) {                                             \
        _Pragma("unroll")                                                        \
        for (int r = 0; r < 4; ++r)                                              \
            pbvX[s4][r] = pb[h * TT + (qrow0 + quad * 4 + r) * T_SEQ + jj_ + s4 * 16 + n16]; \
        kfrX[s4] = *(const bf16x8*)&kb[(bh * T_SEQ + jj_ + s4 * 16 + n16) * DHH + quad * 8]; \
    }                                                                            \
} while (0)

#define TILE_BODY(pbvC, kfrC, jtc) do {                                          \
    const int j0_ = (jtc) * 64;                                                  \
    f32x4 S[4];                                                                  \
    __builtin_amdgcn_s_setprio(1);                                               \
    _Pragma("unroll")                                                            \
    for (int s4 = 0; s4 < 4; ++s4) {                                             \
        f32x4 z = {0.f, 0.f, 0.f, 0.f};                                          \
        S[s4] = __builtin_amdgcn_mfma_f32_16x16x32_bf16(qfr, kfrC[s4], z, 0, 0, 0); \
    }                                                                            \
    __builtin_amdgcn_s_setprio(0);                                               \
    _Pragma("unroll")                                                            \
    for (int s4 = 0; s4 < 4; ++s4)                                               \
        _Pragma("unroll")                                                        \
        for (int r = 0; r < 4; ++r)                                              \
            S[s4][r] += pbvC[s4][r];                                             \
    _Pragma("unroll")                                                            \
    for (int r = 0; r < 4; ++r) {                                                \
        float mx = fmaxf(fmaxf(S[0][r], S[1][r]), fmaxf(S[2][r], S[3][r]));      \
        mx = fmaxf(mx, __shfl_xor(mx, 1));                                       \
        mx = fmaxf(mx, __shfl_xor(mx, 2));                                       \
        mx = fmaxf(mx, __shfl_xor(mx, 4));                                       \
        mx = fmaxf(mx, __shfl_xor(mx, 8));                                       \
        float mnew = fmaxf(m_i[r], mx);                                          \
        float alpha = __expf(m_i[r] - mnew);                                     \
        m_i[r] = mnew;                                                           \
        float lsum = 0.f;                                                        \
        _Pragma("unroll")                                                        \
        for (int s4 = 0; s4 < 4; ++s4) {                                         \
            float p = __expf(S[s4][r] - mnew);                                   \
            S[s4][r] = p;                                                        \
            lsum += p;                                                           \
        }                                                                        \
        l_i[r] = l_i[r] * alpha + lsum;                                          \
        O0[r] *= alpha;                                                          \
        O1[r] *= alpha;                                                          \
    }                                                                            \
    _Pragma("unroll")                                                            \
    for (int s4 = 0; s4 < 4; ++s4)                                               \
        _Pragma("unroll")                                                        \
        for (int r = 0; r < 4; ++r)                                              \
            Ps[w][quad * 4 + r][s4 * 16 + n16] = f2bf(S[s4][r]);                 \
    __builtin_amdgcn_s_setprio(1);                                               \
    _Pragma("unroll")                                                            \
    for (int kc = 0; kc < 2; ++kc) {                                             \
        bf16x8 pfr = *(const bf16x8*)&Ps[w][n16][kc * 32 + quad * 8];            \
        bf16x8 v0 = *(const bf16x8*)&vT[(bh * DHH + n16) * T_SEQ + j0_ + kc * 32 + quad * 8]; \
        bf16x8 v1 = *(const bf16x8*)&vT[(bh * DHH + 16 + n16) * T_SEQ + j0_ + kc * 32 + quad * 8]; \
        O0 = __builtin_amdgcn_mfma_f32_16x16x32_bf16(pfr, v0, O0, 0, 0, 0);      \
        O1 = __builtin_amdgcn_mfma_f32_16x16x32_bf16(pfr, v1, O1, 0, 0, 0);      \
    }                                                                            \
    __builtin_amdgcn_s_setprio(0);                                               \
} while (0)

    PREFETCH(pbvA, kfrA, 0);
    for (int jj = 0; jj < 16; jj += 2) {
        PREFETCH(pbvB, kfrB, jj + 1);
        TILE_BODY(pbvA, kfrA, jj);
        PREFETCH(pbvA, kfrA, jj + 2);   // (jj+2)&15 wraps harmlessly on last iter
        TILE_BODY(pbvB, kfrB, jj + 1);
    }
#undef PREFETCH
#undef TILE_BODY

    // epilogue: finish l reduction (once), 1/l, sigmoid gate, bf16 store
    #pragma unroll
    for (int r = 0; r < 4; ++r) {
        float lr = l_i[r];
        lr += __shfl_xor(lr, 1);
        lr += __shfl_xor(lr, 2);
        lr += __shfl_xor(lr, 4);
        lr += __shfl_xor(lr, 8);
        int t = qrow0 + quad * 4 + r;
        float linv = 1.f / lr;
        float g0 = g[(bh * T_SEQ + t) * DHH + n16];
        float g1 = g[(bh * T_SEQ + t) * DHH + 16 + n16];
        float o0 = O0[r] * linv / (1.f + __expf(-g0));
        float o1 = O1[r] * linv / (1.f + __expf(-g1));
        gated[(b * T_SEQ + t) * CM + h * DHH + n16] = f2bf(o0);
        gated[(b * T_SEQ + t) * CM + h * DHH + 16 + n16] = f2bf(o1);
    }
}

// ---------------------------------------------------------------------------
// K4: y = gated @ W0 via bf16 MFMA. 4x wave parallelism vs prev:
// grid 1024 blocks x 1 wave; block = (m-strip, 4-col-subtile group).
// ---------------------------------------------------------------------------
__global__ __launch_bounds__(64) void out_gemm_mfma(const unsigned short* __restrict__ gb,
                                                    const unsigned short* __restrict__ W0t,
                                                    float* __restrict__ y) {
    const int lane = threadIdx.x;
    const int n16 = lane & 15;
    const int quad = lane >> 4;
    const int m0 = (blockIdx.x >> 2) * 16;
    const int sb = (blockIdx.x & 3) * 4;

    bf16x8 afr[8];
    #pragma unroll
    for (int kc = 0; kc < 8; ++kc)
        afr[kc] = *(const bf16x8*)&gb[(m0 + n16) * 256 + kc * 32 + quad * 8];

    #pragma unroll
    for (int si = 0; si < 4; ++si) {
        const int s = sb + si;
        f32x4 acc = {0.f, 0.f, 0.f, 0.f};
        #pragma unroll
        for (int kc = 0; kc < 8; ++kc) {
            bf16x8 bfr = *(const bf16x8*)&W0t[(s * 16 + n16) * 256 + kc * 32 + quad * 8];
            acc = __builtin_amdgcn_mfma_f32_16x16x32_bf16(afr[kc], bfr, acc, 0, 0, 0);
        }
        #pragma unroll
        for (int r = 0; r < 4; ++r)
            y[(m0 + quad * 4 + r) * 256 + s * 16 + n16] = acc[r];
    }
}

// ---------------------------------------------------------------------------
extern "C" void kernel_launch(void* const* d_in, const int* in_sizes, int n_in,
                              void* d_out, int out_size, void* d_ws, size_t ws_size,
                              hipStream_t stream) {
    const float* x        = (const float*)d_in[0];   // [4,1024,256]
    const float* bias_rep = (const float*)d_in[1];   // [1024,1024,128]
    const float* Wqkv     = (const float*)d_in[2];   // [256,1024]
    const float* W0       = (const float*)d_in[3];   // [256,256]
    const float* Wb       = (const float*)d_in[4];   // [128,8]
    const float* bb       = (const float*)d_in[5];   // [8]

    char* ws = (char*)d_ws;
    float*          pb    = (float*)ws;                 ws += 8LL * 1024 * 1024 * 4;  // 32 MB
    float*          g     = (float*)ws;                 ws += 4LL * 1024 * 1024;      // 4 MB
    unsigned short* qb    = (unsigned short*)ws;        ws += 2LL * 1024 * 1024;      // 2 MB
    unsigned short* kb    = (unsigned short*)ws;        ws += 2LL * 1024 * 1024;
    unsigned short* vT    = (unsigned short*)ws;        ws += 2LL * 1024 * 1024;
    unsigned short* gated = (unsigned short*)ws;        ws += 2LL * 1024 * 1024;
    unsigned short* Wt    = (unsigned short*)ws;        ws += 512LL * 1024;
    unsigned short* W0t   = (unsigned short*)ws;        ws += 128LL * 1024;
    unsigned short* WbT   = (unsigned short*)ws;        // 4 KB
    float* y = (float*)d_out;

    transpose_cast_lds<<<dim3(32, 8), 256, 0, stream>>>(Wqkv, Wt, 1024);
    transpose_cast_lds<<<dim3(8, 8), 256, 0, stream>>>(W0, W0t, 256);
    pad_wb_kernel<<<8, 256, 0, stream>>>(Wb, WbT);
    qkv_gemm_mfma<<<dim3(4, 64), 256, 0, stream>>>(x, Wt, qb, kb, vT, g);
    pair_bias_mfma<<<16384, 256, 0, stream>>>(bias_rep, WbT, bb, pb);
    attn_mfma<<<dim3(16, HEADS, NB), 256, 0, stream>>>(qb, kb, vT, g, pb, gated);
    out_gemm_mfma<<<1024, 64, 0, stream>>>(gated, W0t, y);
}